// Round 5
// baseline (96.212 us; speedup 1.0000x reference)
//
#include <hip/hip_runtime.h>

// MonarchEmbedding: out[t, kr*32+o] = (kr&1)==(k>>5) ? L[k,b1,kr>>1] * R[kr,k&31,o] : 0
// where v = x[t], k = v/786, and L[k,b1,kr>>1] = Lflat[v*16 + (kr>>1)].
// Derivation: p[c]=(c%64)*16+c//64 (perfect_shuffle(64,1024)); BLd[v,col] nonzero
// iff col//16==k, so the einsum over b collapses to a single product. Exact fp32
// match to the reference (the other terms are exact zeros).
//
// R5: VMEM-instruction-mix theory. R4 issued 3 VMEM insts per 1 KiB stored
// (L load + R load + store, loads half-active); the 6 TB/s fill issues 1.
// Stage per-token L rows + needed R slices into LDS cooperatively (5 full-width
// VMEM insts/block), so the compute loop is LDS-read * mul + store only.

#define BL1 786
#define TPB 8   // tokens per block

typedef float vfloat4 __attribute__((ext_vector_type(4)));

__global__ __launch_bounds__(256) void monarch_embed_kernel(
    const int* __restrict__ x,
    const float* __restrict__ L,     // [64, 786, 16] flat
    const float* __restrict__ R,     // [32, 32, 32]  flat
    vfloat4* __restrict__ out)       // [n_tok, 256] float4
{
    __shared__ float sR[TPB][16][32];   // 16 KiB: per token, 16 matching-parity R rows
    __shared__ float sL[TPB][16];       // 512 B : per token, its L row

    const int t    = threadIdx.x;       // 0..255
    const int base = blockIdx.x * TPB;

    int v[TPB], k[TPB], par[TPB];
#pragma unroll
    for (int i = 0; i < TPB; ++i) {
        v[i]   = x[base + i];           // block-uniform -> s_load
        k[i]   = v[i] / BL1;            // magic-mul
        par[i] = k[i] >> 5;
    }

    // Stage L: 128 threads, one float each (one VMEM inst, 8 lines).
    if (t < TPB * 16) {
        const int tok = t >> 4, idx = t & 15;
        sL[tok][idx] = L[v[tok] * 16 + idx];
    }

    // Stage R: 4 rounds x 256 lanes x float4 = 8 tok x 16 rows x 32 floats.
    const int htok = t >> 7;            // 0..1
    const int w    = t & 127;
    const int row_s = w >> 3;           // 0..15
    const int l8    = w & 7;            // 0..7
#pragma unroll
    for (int j = 0; j < 4; ++j) {
        const int tok = j * 2 + htok;
        const int pj  = htok ? par[j * 2 + 1] : par[j * 2];  // cndmask, stays in regs
        const int kj  = htok ? k[j * 2 + 1]   : k[j * 2];
        const int kr  = 2 * row_s + pj;
        const vfloat4 r = *reinterpret_cast<const vfloat4*>(
            R + (kr * 32 + (kj & 31)) * 32 + l8 * 4);
        *reinterpret_cast<vfloat4*>(&sR[tok][row_s][l8 * 4]) = r;
    }

    __syncthreads();

    // Compute + store: per token, 1 ds_read_b32 + 1 ds_read_b128 + 1 store.
    const int kr  = t >> 3;             // 0..31
    const int o0  = (t & 7) << 2;
    const int row = kr >> 1;
#pragma unroll
    for (int i = 0; i < TPB; ++i) {
        vfloat4 val = (vfloat4)(0.f);
        if ((kr & 1) == par[i]) {
            val = sL[i][row] * *reinterpret_cast<const vfloat4*>(&sR[i][row][o0]);
        }
        out[(size_t)(base + i) * 256 + t] = val;
    }
}

extern "C" void kernel_launch(void* const* d_in, const int* in_sizes, int n_in,
                              void* d_out, int out_size, void* d_ws, size_t ws_size,
                              hipStream_t stream) {
    const int*   x = (const int*)d_in[0];
    const float* L = (const float*)d_in[1];
    const float* R = (const float*)d_in[2];
    // d_in[3] = p, unused: closed form derived above for perfect_shuffle(64,1024).

    const int n_tok  = in_sizes[0];          // 8*2048 = 16384
    const int blocks = n_tok / TPB;          // 2048
    monarch_embed_kernel<<<dim3(blocks), dim3(256), 0, stream>>>(
        x, L, R, (vfloat4*)d_out);
}